// Round 8
// baseline (11843.133 us; speedup 1.0000x reference)
//
#include <hip/hip_runtime.h>
#include <math.h>

// B=2, S=2048, H=12, E(head width)=768, HD=9216, FF=3072
#define S_   2048
#define D_   768
#define HD_  9216
#define FF_  3072

// ---------------------------------------------------------------------------
// fp32 SGEMM cores, 64x64 tile, 256 threads (16x16), 4x4 micro-tile, K-tile 16.
// As[k][m] staged transposed; Bs[k][n] straight. Thread (tx,ty) computes
// rows m0+4ty+i, cols n0+4tx+j.
// sgemm_bn: B is [K,N] row-major. sgemm_bt: B^T given as [N,K] row-major.
// ---------------------------------------------------------------------------
__device__ __forceinline__ void sgemm_bn(
    const float* __restrict__ A, int lda,
    const float* __restrict__ B, int ldb,
    int m0, int n0, int kmax, float acc[4][4])
{
    __shared__ float As[16][68];
    __shared__ float Bs[16][68];
    const int tid = threadIdx.x;
    const int tx = tid & 15, ty = tid >> 4;
    const int ar = tid >> 2, ak = (tid & 3) << 2;
    const int bk = tid >> 4, bn = (tid & 15) << 2;

#pragma unroll
    for (int i = 0; i < 4; ++i)
#pragma unroll
        for (int j = 0; j < 4; ++j) acc[i][j] = 0.f;

    for (int k0 = 0; k0 < kmax; k0 += 16) {
        float4 av = *(const float4*)&A[(size_t)(m0 + ar) * lda + k0 + ak];
        As[ak + 0][ar] = av.x; As[ak + 1][ar] = av.y;
        As[ak + 2][ar] = av.z; As[ak + 3][ar] = av.w;
        *(float4*)&Bs[bk][bn] = *(const float4*)&B[(size_t)(k0 + bk) * ldb + n0 + bn];
        __syncthreads();
#pragma unroll
        for (int kk = 0; kk < 16; ++kk) {
            float4 a4 = *(const float4*)&As[kk][ty << 2];
            float4 b4 = *(const float4*)&Bs[kk][tx << 2];
            float aa[4] = {a4.x, a4.y, a4.z, a4.w};
            float bb[4] = {b4.x, b4.y, b4.z, b4.w};
#pragma unroll
            for (int i = 0; i < 4; ++i)
#pragma unroll
                for (int j = 0; j < 4; ++j)
                    acc[i][j] = fmaf(aa[i], bb[j], acc[i][j]);
        }
        __syncthreads();
    }
}

__device__ __forceinline__ void sgemm_bt(
    const float* __restrict__ A, int lda,
    const float* __restrict__ Bt, int ldb,
    int m0, int n0, int kmax, float acc[4][4])
{
    __shared__ float As[16][68];
    __shared__ float Bs[16][68];
    const int tid = threadIdx.x;
    const int tx = tid & 15, ty = tid >> 4;
    const int ar = tid >> 2, ak = (tid & 3) << 2;
    const int bn2 = tid >> 2, bkt = (tid & 3) << 2;

#pragma unroll
    for (int i = 0; i < 4; ++i)
#pragma unroll
        for (int j = 0; j < 4; ++j) acc[i][j] = 0.f;

    for (int k0 = 0; k0 < kmax; k0 += 16) {
        float4 av = *(const float4*)&A[(size_t)(m0 + ar) * lda + k0 + ak];
        As[ak + 0][ar] = av.x; As[ak + 1][ar] = av.y;
        As[ak + 2][ar] = av.z; As[ak + 3][ar] = av.w;
        float4 bv = *(const float4*)&Bt[(size_t)(n0 + bn2) * ldb + k0 + bkt];
        Bs[bkt + 0][bn2] = bv.x; Bs[bkt + 1][bn2] = bv.y;
        Bs[bkt + 2][bn2] = bv.z; Bs[bkt + 3][bn2] = bv.w;
        __syncthreads();
#pragma unroll
        for (int kk = 0; kk < 16; ++kk) {
            float4 a4 = *(const float4*)&As[kk][ty << 2];
            float4 b4 = *(const float4*)&Bs[kk][tx << 2];
            float aa[4] = {a4.x, a4.y, a4.z, a4.w};
            float bb[4] = {b4.x, b4.y, b4.z, b4.w};
#pragma unroll
            for (int i = 0; i < 4; ++i)
#pragma unroll
                for (int j = 0; j < 4; ++j)
                    acc[i][j] = fmaf(aa[i], bb[j], acc[i][j]);
        }
        __syncthreads();
    }
}

// ---------------------------------------------------------------------------
// One head, one batch, einsum 'bsd,hde->bhse' convention:
// Out[s][e] = sum_d Xb[s,d] * W[d][e]. grid (12, 32).
// ---------------------------------------------------------------------------
__global__ __launch_bounds__(256) void proj_kernel(
    const float* __restrict__ Xb, const float* __restrict__ W,
    float* __restrict__ Out)
{
    const int m0 = blockIdx.y * 64, n0 = blockIdx.x * 64;
    float acc[4][4];
    sgemm_bn(Xb, D_, W, D_, m0, n0, D_, acc);
    const int tx = threadIdx.x & 15, ty = threadIdx.x >> 4;
#pragma unroll
    for (int i = 0; i < 4; ++i)
#pragma unroll
        for (int j = 0; j < 4; ++j)
            Out[(size_t)(m0 + 4 * ty + i) * D_ + n0 + 4 * tx + j] = acc[i][j];
}

// ---------------------------------------------------------------------------
// Full score matrix: Sc[q][k] = Q[q,:].K[k,:] (unscaled fp32). grid (32, 32).
// ---------------------------------------------------------------------------
__global__ __launch_bounds__(256) void scores_kernel(
    const float* __restrict__ Q, const float* __restrict__ K,
    float* __restrict__ Sc)
{
    const int m0 = blockIdx.y * 64, n0 = blockIdx.x * 64;
    float acc[4][4];
    sgemm_bt(Q, D_, K, D_, m0, n0, D_, acc);
    const int tx = threadIdx.x & 15, ty = threadIdx.x >> 4;
#pragma unroll
    for (int i = 0; i < 4; ++i)
#pragma unroll
        for (int j = 0; j < 4; ++j)
            Sc[(size_t)(m0 + 4 * ty + i) * S_ + n0 + 4 * tx + j] = acc[i][j];
}

// ---------------------------------------------------------------------------
// Causal softmax row q (applies 1/sqrt(768)); zero for k>q. grid (2048).
// ---------------------------------------------------------------------------
__global__ __launch_bounds__(256) void softmax_kernel(float* __restrict__ Sc)
{
    const int qi = blockIdx.x;
    float* row = Sc + (size_t)qi * S_;
    const float scale = 0.03608439182435161f;  // 1/sqrt(768)
    const int tid = threadIdx.x;
    const int wave = tid >> 6, lane = tid & 63;

    float xv[8];
    float m = -1e30f;
#pragma unroll
    for (int i = 0; i < 8; ++i) {
        int idx = tid + i * 256;
        xv[i] = (idx <= qi) ? row[idx] * scale : -1e30f;
        m = fmaxf(m, xv[i]);
    }
    for (int o = 32; o > 0; o >>= 1) m = fmaxf(m, __shfl_xor(m, o));
    __shared__ float redm[4];
    if (lane == 0) redm[wave] = m;
    __syncthreads();
    m = fmaxf(fmaxf(redm[0], redm[1]), fmaxf(redm[2], redm[3]));

    float e[8];
    float s = 0.f;
#pragma unroll
    for (int i = 0; i < 8; ++i) {
        int idx = tid + i * 256;
        e[i] = (idx <= qi) ? expf(xv[i] - m) : 0.f;
        s += e[i];
    }
    for (int o = 32; o > 0; o >>= 1) s += __shfl_xor(s, o);
    __shared__ float reds[4];
    if (lane == 0) reds[wave] = s;
    __syncthreads();
    s = reds[0] + reds[1] + reds[2] + reds[3];
    const float inv = 1.f / s;
#pragma unroll
    for (int i = 0; i < 8; ++i) {
        int idx = tid + i * 256;
        row[idx] = e[i] * inv;
    }
}

// ---------------------------------------------------------------------------
// ctx: Ctx[q][e] = sum_k P[q,k] * V[k][e], full K=2048. grid (12, 32).
// ---------------------------------------------------------------------------
__global__ __launch_bounds__(256) void ctx_kernel(
    const float* __restrict__ Sc, const float* __restrict__ V,
    float* __restrict__ Ctx)
{
    const int m0 = blockIdx.y * 64, n0 = blockIdx.x * 64;
    float acc[4][4];
    sgemm_bn(Sc, S_, V, D_, m0, n0, S_, acc);
    const int tx = threadIdx.x & 15, ty = threadIdx.x >> 4;
#pragma unroll
    for (int i = 0; i < 4; ++i)
#pragma unroll
        for (int j = 0; j < 4; ++j)
            Ctx[(size_t)(m0 + 4 * ty + i) * D_ + n0 + 4 * tx + j] = acc[i][j];
}

// ---------------------------------------------------------------------------
// Accumulate: AttnB[m][n] += sum_e Ctx[m][e] * WoH[n*9216 + e], e<768.
// WoH pre-offset to head h's column block (ctx @ Wo^T). grid (12, 32).
// ---------------------------------------------------------------------------
__global__ __launch_bounds__(256) void outproj_kernel(
    const float* __restrict__ Ctx, const float* __restrict__ WoH,
    float* __restrict__ AttnB)
{
    const int m0 = blockIdx.y * 64, n0 = blockIdx.x * 64;
    float acc[4][4];
    sgemm_bt(Ctx, D_, WoH, HD_, m0, n0, D_, acc);
    const int tx = threadIdx.x & 15, ty = threadIdx.x >> 4;
#pragma unroll
    for (int i = 0; i < 4; ++i)
#pragma unroll
        for (int j = 0; j < 4; ++j)
            AttnB[(size_t)(m0 + 4 * ty + i) * D_ + n0 + 4 * tx + j] += acc[i][j];
}

// ---------------------------------------------------------------------------
// LayerNorm (no affine, eps=1e-5): rows [off, off+1024) of Attn -> LnC fp32.
// ---------------------------------------------------------------------------
__global__ __launch_bounds__(256) void ln_kernel(
    const float* __restrict__ Attn, float* __restrict__ LnC, int off)
{
    const int row = blockIdx.x;
    const float* a = Attn + (size_t)(off + row) * D_;
    const int tid = threadIdx.x;
    const int wave = tid >> 6, lane = tid & 63;
    float v0 = a[tid], v1 = a[tid + 256], v2 = a[tid + 512];
    float s  = v0 + v1 + v2;
    float sq = v0 * v0 + v1 * v1 + v2 * v2;
    for (int o = 32; o > 0; o >>= 1) { s += __shfl_xor(s, o); sq += __shfl_xor(sq, o); }
    __shared__ float rs[4], rq[4];
    if (lane == 0) { rs[wave] = s; rq[wave] = sq; }
    __syncthreads();
    s  = rs[0] + rs[1] + rs[2] + rs[3];
    sq = rq[0] + rq[1] + rq[2] + rq[3];
    const float mean = s * (1.f / 768.f);
    float var = sq * (1.f / 768.f) - mean * mean;
    var = fmaxf(var, 0.f);
    const float rstd = rsqrtf(var + 1e-5f);
    float* o = LnC + (size_t)row * D_;
    o[tid]       = (v0 - mean) * rstd;
    o[tid + 256] = (v1 - mean) * rstd;
    o[tid + 512] = (v2 - mean) * rstd;
}

// ---------------------------------------------------------------------------
// FFN1 + exact GELU on 1024-row chunk: H1C = gelu(LnC . F1^T). grid (48, 16).
// ---------------------------------------------------------------------------
__global__ __launch_bounds__(256) void ffn1_kernel(
    const float* __restrict__ LnC, const float* __restrict__ F1,
    float* __restrict__ H1C)
{
    const int m0 = blockIdx.y * 64, n0 = blockIdx.x * 64;
    float acc[4][4];
    sgemm_bt(LnC, D_, F1, D_, m0, n0, D_, acc);
    const int tx = threadIdx.x & 15, ty = threadIdx.x >> 4;
#pragma unroll
    for (int i = 0; i < 4; ++i)
#pragma unroll
        for (int j = 0; j < 4; ++j) {
            float v = acc[i][j];
            float gl = 0.5f * v * (1.f + erff(v * 0.70710678118654752f));
            H1C[(size_t)(m0 + 4 * ty + i) * FF_ + n0 + 4 * tx + j] = gl;
        }
}

// ---------------------------------------------------------------------------
// FFN2 + residual chunk -> d_out (FP32!) rows [off, off+1024). grid (12, 16).
// THE round-8 change: reference output dtype is float32 -> d_out is float*.
// ---------------------------------------------------------------------------
__global__ __launch_bounds__(256) void ffn2_kernel(
    const float* __restrict__ H1C, const float* __restrict__ F2,
    const float* __restrict__ Attn, float* __restrict__ Out, int off)
{
    const int m0 = blockIdx.y * 64, n0 = blockIdx.x * 64;
    float acc[4][4];
    sgemm_bt(H1C, FF_, F2, FF_, m0, n0, FF_, acc);
    const int tx = threadIdx.x & 15, ty = threadIdx.x >> 4;
#pragma unroll
    for (int i = 0; i < 4; ++i)
#pragma unroll
        for (int j = 0; j < 4; ++j) {
            size_t idx = (size_t)(off + m0 + 4 * ty + i) * D_ + n0 + 4 * tx + j;
            Out[idx] = acc[i][j] + Attn[idx];
        }
}

// ---------------------------------------------------------------------------
// kernel_launch — round 6 structure verbatim; only change: fp32 output.
// Workspace: 70,254,592 B.
// ---------------------------------------------------------------------------
extern "C" void kernel_launch(void* const* d_in, const int* in_sizes, int n_in,
                              void* d_out, int out_size, void* d_ws, size_t ws_size,
                              hipStream_t stream)
{
    // identify inputs by element count (x=3145728, ff=2359296, weights rest)
    int ix = -1, iw[4], nw = 0, iff[2], nf = 0;
    for (int i = 0; i < 7; ++i) {
        long sz = in_sizes[i];
        if (sz == 3145728L) ix = i;
        else if (sz == 2359296L) { if (nf < 2) iff[nf++] = i; }
        else { if (nw < 4) iw[nw++] = i; }
    }
    if (ix < 0 || nw != 4 || nf != 2) {
        ix = 0; iw[0] = 1; iw[1] = 2; iw[2] = 3; iw[3] = 4; iff[0] = 5; iff[1] = 6;
    }
    const float* x; const float *Wq, *Wk, *Wv, *Wo, *F1, *F2;
    x  = (const float*)d_in[ix];
    F1 = (const float*)d_in[iff[0]];
    F2 = (const float*)d_in[iff[1]];
    if (ix == 0) {           // dict order: x, W_q, W_k, W_v, W_o, ff_w1, ff_w2
        Wq = (const float*)d_in[iw[0]]; Wk = (const float*)d_in[iw[1]];
        Wv = (const float*)d_in[iw[2]]; Wo = (const float*)d_in[iw[3]];
    } else {                 // alphabetical: W_k, W_o, W_q, W_v, ff_w1, ff_w2, x
        Wk = (const float*)d_in[iw[0]]; Wo = (const float*)d_in[iw[1]];
        Wq = (const float*)d_in[iw[2]]; Wv = (const float*)d_in[iw[3]];
    }

    char* p = (char*)d_ws;
    float* Qh   = (float*)p;  p += 6291456;    // [2048,768]
    float* Kh   = (float*)p;  p += 6291456;
    float* Vh   = (float*)p;  p += 6291456;
    float* Ctxh = (float*)p;  p += 6291456;
    float* Sc   = (float*)p;  p += 16777216;   // [2048,2048]
    float* Attn = (float*)p;  p += 12582912;   // [4096,768]
    float* LnC  = (float*)p;  p += 3145728;    // [1024,768]
    float* H1C  = (float*)p;                   // [1024,3072]

    dim3 blk(256);
    hipMemsetAsync(Attn, 0, 12582912, stream);

    for (int b = 0; b < 2; ++b) {
        const float* xb = x + (size_t)b * S_ * D_;
        float* AttnB = Attn + (size_t)b * S_ * D_;
        for (int h = 0; h < 12; ++h) {
            const size_t wo = (size_t)h * D_ * D_;
            proj_kernel<<<dim3(12, 32), blk, 0, stream>>>(xb, Wq + wo, Qh);
            proj_kernel<<<dim3(12, 32), blk, 0, stream>>>(xb, Wk + wo, Kh);
            proj_kernel<<<dim3(12, 32), blk, 0, stream>>>(xb, Wv + wo, Vh);
            scores_kernel<<<dim3(32, 32), blk, 0, stream>>>(Qh, Kh, Sc);
            softmax_kernel<<<dim3(2048), blk, 0, stream>>>(Sc);
            ctx_kernel<<<dim3(12, 32), blk, 0, stream>>>(Sc, Vh, Ctxh);
            outproj_kernel<<<dim3(12, 32), blk, 0, stream>>>(
                Ctxh, Wo + (size_t)h * D_, AttnB);
        }
    }

    for (int mc = 0; mc < 4; ++mc) {
        const int off = mc * 1024;
        ln_kernel<<<dim3(1024), blk, 0, stream>>>(Attn, LnC, off);
        ffn1_kernel<<<dim3(48, 16), blk, 0, stream>>>(LnC, F1, H1C);
        ffn2_kernel<<<dim3(12, 16), blk, 0, stream>>>(H1C, F2, Attn, (float*)d_out, off);
    }
}

// Round 9
// 3068.730 us; speedup vs baseline: 3.8593x; 3.8593x over previous
//
#include <hip/hip_runtime.h>
#include <math.h>

// B=2, S=2048, H=12, E(head width)=768, HD=9216, FF=3072
#define S_   2048
#define D_   768
#define HD_  9216
#define FF_  3072

typedef float  f32x4  __attribute__((ext_vector_type(4)));
typedef __bf16 bf16x8 __attribute__((ext_vector_type(8)));

__device__ __forceinline__ ushort f2bf(float v) {
    return __builtin_bit_cast(ushort, (__bf16)v);   // RNE fp32->bf16
}

// ---------------------------------------------------------------------------
// Verified 64x64 bf16 MFMA GEMM tile (r3/r4 core, HW-validated vs fp32
// pipeline): C = A[M,K] * Bt[N,K]^T, fp32 accum. 4 waves, 16x16x32 MFMA.
//   A-frag: A[m=lane&15][k=quad*8+j];  B-frag: Bt[n=lane&15][k=quad*8+j]
//   C/D   : col=lane&15, row=quad*4+reg
// ---------------------------------------------------------------------------
__device__ __forceinline__ void gemm_core(
    const ushort* __restrict__ A, int lda,
    const ushort* __restrict__ Bt, int ldb,
    int m0, int n0, int kmax, f32x4 acc[4])
{
    __shared__ __align__(16) ushort lsa[64 * 40];  // pad 32->40 (2-way alias free)
    __shared__ __align__(16) ushort lsb[64 * 40];
    const int tid  = threadIdx.x;
    const int r    = tid >> 2;
    const int cc   = (tid & 3) << 3;
    const int lane = tid & 63;
    const int wave = tid >> 6;
    const int l16  = lane & 15;
    const int quad = lane >> 4;

#pragma unroll
    for (int j = 0; j < 4; ++j) acc[j] = (f32x4){0.f, 0.f, 0.f, 0.f};

    for (int k0 = 0; k0 < kmax; k0 += 32) {
        *(uint4*)&lsa[r * 40 + cc] =
            *(const uint4*)&A[(size_t)(m0 + r) * lda + k0 + cc];
        *(uint4*)&lsb[r * 40 + cc] =
            *(const uint4*)&Bt[(size_t)(n0 + r) * ldb + k0 + cc];
        __syncthreads();
        bf16x8 af = *(const bf16x8*)&lsa[(wave * 16 + l16) * 40 + quad * 8];
#pragma unroll
        for (int j = 0; j < 4; ++j) {
            bf16x8 bv = *(const bf16x8*)&lsb[(j * 16 + l16) * 40 + quad * 8];
            acc[j] = __builtin_amdgcn_mfma_f32_16x16x32_bf16(af, bv, acc[j], 0, 0, 0);
        }
        __syncthreads();
    }
}

// ---------------------------------------------------------------------------
// fp32 -> bf16 convert (n multiple of 1024). grid-stride, float4 loads.
// ---------------------------------------------------------------------------
__global__ __launch_bounds__(256) void convert_kernel(
    const float* __restrict__ in, ushort* __restrict__ out, long n)
{
    long i = ((long)blockIdx.x * 256 + threadIdx.x) * 4;
    const long stride = (long)gridDim.x * 1024;
    for (; i < n; i += stride) {
        float4 v = *(const float4*)&in[i];
        out[i + 0] = f2bf(v.x); out[i + 1] = f2bf(v.y);
        out[i + 2] = f2bf(v.z); out[i + 3] = f2bf(v.w);
    }
}

// ---------------------------------------------------------------------------
// fused fp32->bf16 convert + transpose, 32x32 LDS tiles: in fp32 [R,C] ->
// out bf16 [C,R]. grid (C/32, R/32).
// ---------------------------------------------------------------------------
__global__ __launch_bounds__(256) void convt_kernel(
    const float* __restrict__ in, ushort* __restrict__ out, int R, int C)
{
    const int c0 = blockIdx.x * 32;
    const int r0 = blockIdx.y * 32;
    __shared__ ushort t[32][33];
    const int tid = threadIdx.x;
    const int r = tid >> 3;
    const int c = (tid & 7) << 2;
    float4 v = *(const float4*)&in[(size_t)(r0 + r) * C + c0 + c];
    t[r][c + 0] = f2bf(v.x); t[r][c + 1] = f2bf(v.y);
    t[r][c + 2] = f2bf(v.z); t[r][c + 3] = f2bf(v.w);
    __syncthreads();
    ushort4 o;
    o.x = t[c + 0][r]; o.y = t[c + 1][r]; o.z = t[c + 2][r]; o.w = t[c + 3][r];
    *(ushort4*)&out[(size_t)(c0 + r) * R + r0 + c] = o;
}

// ---------------------------------------------------------------------------
// bf16 transpose (for V), 32x32 LDS tiles. [R,C] -> [C,R]. grid (C/32, R/32).
// ---------------------------------------------------------------------------
__global__ __launch_bounds__(256) void transpose_kernel(
    const ushort* __restrict__ in, ushort* __restrict__ out, int R, int C)
{
    const int c0 = blockIdx.x * 32;
    const int r0 = blockIdx.y * 32;
    __shared__ ushort t[32][33];
    const int tid = threadIdx.x;
    const int r = tid >> 3;
    const int c = (tid & 7) << 2;
    ushort4 v = *(const ushort4*)&in[(size_t)(r0 + r) * C + c0 + c];
    t[r][c + 0] = v.x; t[r][c + 1] = v.y; t[r][c + 2] = v.z; t[r][c + 3] = v.w;
    __syncthreads();
    ushort4 o;
    o.x = t[c + 0][r]; o.y = t[c + 1][r]; o.z = t[c + 2][r]; o.w = t[c + 3][r];
    *(ushort4*)&out[(size_t)(c0 + r) * R + r0 + c] = o;
}

// ---------------------------------------------------------------------------
// Projection (einsum 'sd,de->se'): Out[s][e] = sum_d Xb[s,d] * Wt[e][d]
// (Wt = W^T, bf16). grid (12, 32).
// ---------------------------------------------------------------------------
__global__ __launch_bounds__(256, 2) void proj_kernel(
    const ushort* __restrict__ Xb, const ushort* __restrict__ Wt,
    ushort* __restrict__ Out)
{
    const int m0 = blockIdx.y * 64, n0 = blockIdx.x * 64;
    f32x4 acc[4];
    gemm_core(Xb, D_, Wt, D_, m0, n0, D_, acc);
    const int lane = threadIdx.x & 63, wave = threadIdx.x >> 6;
    const int l16 = lane & 15, quad = lane >> 4;
#pragma unroll
    for (int j = 0; j < 4; ++j)
#pragma unroll
        for (int i = 0; i < 4; ++i) {
            int rr = m0 + wave * 16 + quad * 4 + i;
            int nc = n0 + j * 16 + l16;
            Out[(size_t)rr * D_ + nc] = f2bf(acc[j][i]);
        }
}

// ---------------------------------------------------------------------------
// scores: Sc[q][k] = Q[q,:].K[k,:] (bf16, unscaled). grid (32, 32);
// tiles fully above causal diagonal skipped.
// ---------------------------------------------------------------------------
__global__ __launch_bounds__(256, 2) void scores_kernel(
    const ushort* __restrict__ Q, const ushort* __restrict__ K,
    ushort* __restrict__ Sc)
{
    const int m0 = blockIdx.y * 64, n0 = blockIdx.x * 64;
    if (n0 >= m0 + 64) return;
    f32x4 acc[4];
    gemm_core(Q, D_, K, D_, m0, n0, D_, acc);
    const int lane = threadIdx.x & 63, wave = threadIdx.x >> 6;
    const int l16 = lane & 15, quad = lane >> 4;
#pragma unroll
    for (int j = 0; j < 4; ++j)
#pragma unroll
        for (int i = 0; i < 4; ++i) {
            int rr = m0 + wave * 16 + quad * 4 + i;
            int nc = n0 + j * 16 + l16;
            Sc[(size_t)rr * S_ + nc] = f2bf(acc[j][i]);
        }
}

// ---------------------------------------------------------------------------
// Causal softmax row q in place (scale 1/sqrt(768)), bf16; zeros k>q.
// grid (2048).
// ---------------------------------------------------------------------------
__global__ __launch_bounds__(256) void softmax_kernel(ushort* __restrict__ Sc)
{
    const int qi = blockIdx.x;
    __bf16* row = (__bf16*)(Sc + (size_t)qi * S_);
    const float scale = 0.03608439182435161f;  // 1/sqrt(768)
    const int tid = threadIdx.x;
    const int wave = tid >> 6, lane = tid & 63;

    float xv[8];
    float m = -1e30f;
#pragma unroll
    for (int i = 0; i < 8; ++i) {
        int idx = tid + i * 256;
        xv[i] = (idx <= qi) ? (float)row[idx] * scale : -1e30f;
        m = fmaxf(m, xv[i]);
    }
    for (int o = 32; o > 0; o >>= 1) m = fmaxf(m, __shfl_xor(m, o));
    __shared__ float redm[4];
    if (lane == 0) redm[wave] = m;
    __syncthreads();
    m = fmaxf(fmaxf(redm[0], redm[1]), fmaxf(redm[2], redm[3]));

    float e[8];
    float s = 0.f;
#pragma unroll
    for (int i = 0; i < 8; ++i) {
        int idx = tid + i * 256;
        e[i] = (idx <= qi) ? __expf(xv[i] - m) : 0.f;
        s += e[i];
    }
    for (int o = 32; o > 0; o >>= 1) s += __shfl_xor(s, o);
    __shared__ float reds[4];
    if (lane == 0) reds[wave] = s;
    __syncthreads();
    s = reds[0] + reds[1] + reds[2] + reds[3];
    const float inv = 1.f / s;
#pragma unroll
    for (int i = 0; i < 8; ++i) {
        int idx = tid + i * 256;
        row[idx] = (__bf16)(e[i] * inv);
    }
}

// ---------------------------------------------------------------------------
// ctx: Ctx[q][e] = sum_k P[q,k] * Vt[e][k]; k-loop stops at diagonal.
// grid (12, 32).
// ---------------------------------------------------------------------------
__global__ __launch_bounds__(256, 2) void ctx_kernel(
    const ushort* __restrict__ Sc, const ushort* __restrict__ Vt,
    ushort* __restrict__ Ctx)
{
    const int m0 = blockIdx.y * 64, n0 = blockIdx.x * 64;
    f32x4 acc[4];
    gemm_core(Sc, S_, Vt, S_, m0, n0, m0 + 64, acc);
    const int lane = threadIdx.x & 63, wave = threadIdx.x >> 6;
    const int l16 = lane & 15, quad = lane >> 4;
#pragma unroll
    for (int j = 0; j < 4; ++j)
#pragma unroll
        for (int i = 0; i < 4; ++i) {
            int rr = m0 + wave * 16 + quad * 4 + i;
            int nc = n0 + j * 16 + l16;
            Ctx[(size_t)rr * D_ + nc] = f2bf(acc[j][i]);
        }
}

// ---------------------------------------------------------------------------
// Accumulating out-projection: AttnB[m][n] += Ctx[m,:768] . Wob[n][h*768+:768]
// (Wob bf16 [768][9216], pre-offset by h*768; ldb=9216). grid (12, 32).
// ---------------------------------------------------------------------------
__global__ __launch_bounds__(256, 2) void outproj_kernel(
    const ushort* __restrict__ Ctx, const ushort* __restrict__ WoH,
    float* __restrict__ AttnB)
{
    const int m0 = blockIdx.y * 64, n0 = blockIdx.x * 64;
    f32x4 acc[4];
    gemm_core(Ctx, D_, WoH, HD_, m0, n0, D_, acc);
    const int lane = threadIdx.x & 63, wave = threadIdx.x >> 6;
    const int l16 = lane & 15, quad = lane >> 4;
#pragma unroll
    for (int j = 0; j < 4; ++j)
#pragma unroll
        for (int i = 0; i < 4; ++i) {
            int rr = m0 + wave * 16 + quad * 4 + i;
            int nc = n0 + j * 16 + l16;
            AttnB[(size_t)rr * D_ + nc] += acc[j][i];
        }
}

// ---------------------------------------------------------------------------
// LayerNorm (no affine, eps=1e-5), fp32 in -> bf16 out, rows [off,off+1024).
// ---------------------------------------------------------------------------
__global__ __launch_bounds__(256) void ln_kernel(
    const float* __restrict__ Attn, ushort* __restrict__ LnC, int off)
{
    const int row = blockIdx.x;
    const float* a = Attn + (size_t)(off + row) * D_;
    const int tid = threadIdx.x;
    const int wave = tid >> 6, lane = tid & 63;
    float v0 = a[tid], v1 = a[tid + 256], v2 = a[tid + 512];
    float s  = v0 + v1 + v2;
    float sq = v0 * v0 + v1 * v1 + v2 * v2;
    for (int o = 32; o > 0; o >>= 1) { s += __shfl_xor(s, o); sq += __shfl_xor(sq, o); }
    __shared__ float rs[4], rq[4];
    if (lane == 0) { rs[wave] = s; rq[wave] = sq; }
    __syncthreads();
    s  = rs[0] + rs[1] + rs[2] + rs[3];
    sq = rq[0] + rq[1] + rq[2] + rq[3];
    const float mean = s * (1.f / 768.f);
    float var = sq * (1.f / 768.f) - mean * mean;
    var = fmaxf(var, 0.f);
    const float rstd = rsqrtf(var + 1e-5f);
    ushort* o = LnC + (size_t)row * D_;
    o[tid]       = f2bf((v0 - mean) * rstd);
    o[tid + 256] = f2bf((v1 - mean) * rstd);
    o[tid + 512] = f2bf((v2 - mean) * rstd);
}

// ---------------------------------------------------------------------------
// FFN1 + exact GELU on 1024-row chunk: H1C = gelu(LnC . F1b^T). grid (48, 16).
// ---------------------------------------------------------------------------
__global__ __launch_bounds__(256, 2) void ffn1_kernel(
    const ushort* __restrict__ LnC, const ushort* __restrict__ F1b,
    ushort* __restrict__ H1C)
{
    const int m0 = blockIdx.y * 64, n0 = blockIdx.x * 64;
    f32x4 acc[4];
    gemm_core(LnC, D_, F1b, D_, m0, n0, D_, acc);
    const int lane = threadIdx.x & 63, wave = threadIdx.x >> 6;
    const int l16 = lane & 15, quad = lane >> 4;
#pragma unroll
    for (int j = 0; j < 4; ++j)
#pragma unroll
        for (int i = 0; i < 4; ++i) {
            int rr = m0 + wave * 16 + quad * 4 + i;
            int nc = n0 + j * 16 + l16;
            float v = acc[j][i];
            float gl = 0.5f * v * (1.f + erff(v * 0.70710678118654752f));
            H1C[(size_t)rr * FF_ + nc] = f2bf(gl);
        }
}

// ---------------------------------------------------------------------------
// FFN2 + residual -> d_out fp32, rows [off, off+1024). grid (12, 16).
// ---------------------------------------------------------------------------
__global__ __launch_bounds__(256, 2) void ffn2_kernel(
    const ushort* __restrict__ H1C, const ushort* __restrict__ F2b,
    const float* __restrict__ Attn, float* __restrict__ Out, int off)
{
    const int m0 = blockIdx.y * 64, n0 = blockIdx.x * 64;
    f32x4 acc[4];
    gemm_core(H1C, FF_, F2b, FF_, m0, n0, FF_, acc);
    const int lane = threadIdx.x & 63, wave = threadIdx.x >> 6;
    const int l16 = lane & 15, quad = lane >> 4;
#pragma unroll
    for (int j = 0; j < 4; ++j)
#pragma unroll
        for (int i = 0; i < 4; ++i) {
            size_t idx = (size_t)(off + m0 + wave * 16 + quad * 4 + i) * D_
                       + n0 + j * 16 + l16;
            Out[idx] = acc[j][i] + Attn[idx];
        }
}

// ---------------------------------------------------------------------------
// kernel_launch — r8 loop structure, bf16 MFMA GEMMs, fp32 out.
// Workspace total: 77,987,840 B (< established ws_size >= 81 MB).
// ---------------------------------------------------------------------------
extern "C" void kernel_launch(void* const* d_in, const int* in_sizes, int n_in,
                              void* d_out, int out_size, void* d_ws, size_t ws_size,
                              hipStream_t stream)
{
    // identify inputs by element count (x=3145728, ff=2359296, weights rest)
    int ix = -1, iw[4], nw = 0, iff[2], nf = 0;
    for (int i = 0; i < 7; ++i) {
        long sz = in_sizes[i];
        if (sz == 3145728L) ix = i;
        else if (sz == 2359296L) { if (nf < 2) iff[nf++] = i; }
        else { if (nw < 4) iw[nw++] = i; }
    }
    if (ix < 0 || nw != 4 || nf != 2) {
        ix = 0; iw[0] = 1; iw[1] = 2; iw[2] = 3; iw[3] = 4; iff[0] = 5; iff[1] = 6;
    }
    const float* x; const float *Wq, *Wk, *Wv, *Wo, *F1, *F2;
    x  = (const float*)d_in[ix];
    F1 = (const float*)d_in[iff[0]];
    F2 = (const float*)d_in[iff[1]];
    if (ix == 0) {           // dict order
        Wq = (const float*)d_in[iw[0]]; Wk = (const float*)d_in[iw[1]];
        Wv = (const float*)d_in[iw[2]]; Wo = (const float*)d_in[iw[3]];
    } else {                 // alphabetical
        Wk = (const float*)d_in[iw[0]]; Wo = (const float*)d_in[iw[1]];
        Wq = (const float*)d_in[iw[2]]; Wv = (const float*)d_in[iw[3]];
    }

    char* p = (char*)d_ws;
    ushort* Xb   = (ushort*)p;  p += 6291456;    // [4096,768] bf16
    ushort* Wob  = (ushort*)p;  p += 14155776;   // [768,9216] bf16
    ushort* F1b  = (ushort*)p;  p += 4718592;    // [3072,768] bf16
    ushort* F2b  = (ushort*)p;  p += 4718592;    // [768,3072] bf16
    ushort* Wqt  = (ushort*)p;  p += 1179648;    // [768,768]  bf16 (W^T)
    ushort* Wkt  = (ushort*)p;  p += 1179648;
    ushort* Wvt  = (ushort*)p;  p += 1179648;
    ushort* Qh   = (ushort*)p;  p += 3145728;    // [2048,768] bf16
    ushort* Kh   = (ushort*)p;  p += 3145728;
    ushort* Vh   = (ushort*)p;  p += 3145728;
    ushort* Vth  = (ushort*)p;  p += 3145728;    // [768,2048] bf16
    ushort* Sc   = (ushort*)p;  p += 8388608;    // [2048,2048] bf16
    ushort* Ctxh = (ushort*)p;  p += 3145728;    // [2048,768] bf16
    float*  Attn = (float*)p;   p += 12582912;   // [4096,768] fp32
    ushort* LnC  = (ushort*)p;  p += 1572864;    // [1024,768] bf16
    ushort* H1C  = (ushort*)p;                   // [1024,3072] bf16

    dim3 blk(256);
    hipMemsetAsync(Attn, 0, 12582912, stream);

    // one-shot converts
    convert_kernel<<<dim3(1024), blk, 0, stream>>>(x,  Xb,  3145728L);
    convert_kernel<<<dim3(1024), blk, 0, stream>>>(Wo, Wob, 7077888L);
    convert_kernel<<<dim3(1024), blk, 0, stream>>>(F1, F1b, 2359296L);
    convert_kernel<<<dim3(1024), blk, 0, stream>>>(F2, F2b, 2359296L);

    for (int h = 0; h < 12; ++h) {
        const size_t wo = (size_t)h * D_ * D_;
        convt_kernel<<<dim3(24, 24), blk, 0, stream>>>(Wq + wo, Wqt, 768, 768);
        convt_kernel<<<dim3(24, 24), blk, 0, stream>>>(Wk + wo, Wkt, 768, 768);
        convt_kernel<<<dim3(24, 24), blk, 0, stream>>>(Wv + wo, Wvt, 768, 768);
        for (int b = 0; b < 2; ++b) {
            const ushort* xb = Xb + (size_t)b * S_ * D_;
            float* AttnB = Attn + (size_t)b * S_ * D_;
            proj_kernel<<<dim3(12, 32), blk, 0, stream>>>(xb, Wqt, Qh);
            proj_kernel<<<dim3(12, 32), blk, 0, stream>>>(xb, Wkt, Kh);
            proj_kernel<<<dim3(12, 32), blk, 0, stream>>>(xb, Wvt, Vh);
            transpose_kernel<<<dim3(24, 64), blk, 0, stream>>>(Vh, Vth, 2048, 768);
            scores_kernel<<<dim3(32, 32), blk, 0, stream>>>(Qh, Kh, Sc);
            softmax_kernel<<<dim3(2048), blk, 0, stream>>>(Sc);
            ctx_kernel<<<dim3(12, 32), blk, 0, stream>>>(Sc, Vth, Ctxh);
            outproj_kernel<<<dim3(12, 32), blk, 0, stream>>>(
                Ctxh, Wob + (size_t)h * D_, AttnB);
        }
    }

    for (int mc = 0; mc < 4; ++mc) {
        const int off = mc * 1024;
        ln_kernel<<<dim3(1024), blk, 0, stream>>>(Attn, LnC, off);
        ffn1_kernel<<<dim3(48, 16), blk, 0, stream>>>(LnC, F1b, H1C);
        ffn2_kernel<<<dim3(12, 16), blk, 0, stream>>>(H1C, F2b, Attn, (float*)d_out, off);
    }
}

// Round 10
// 1754.746 us; speedup vs baseline: 6.7492x; 1.7488x over previous
//
#include <hip/hip_runtime.h>
#include <math.h>

// B=2, S=2048, H=12, E(head width)=768, HD=9216, FF=3072
#define S_   2048
#define D_   768
#define HD_  9216
#define FF_  3072

typedef float  f32x4  __attribute__((ext_vector_type(4)));
typedef __bf16 bf16x8 __attribute__((ext_vector_type(8)));

__device__ __forceinline__ ushort f2bf(float v) {
    return __builtin_bit_cast(ushort, (__bf16)v);   // RNE fp32->bf16
}

// async global->LDS, 16B per lane; LDS dest = wave-uniform base + lane*16
__device__ __forceinline__ void load_lds16(const ushort* g, ushort* l) {
    __builtin_amdgcn_global_load_lds(
        (const __attribute__((address_space(1))) void*)g,
        (__attribute__((address_space(3))) void*)l, 16, 0, 0);
}

// ---------------------------------------------------------------------------
// 128x128 bf16 MFMA GEMM core (m97 recipe): C = A[M,K] * Bt[N,K]^T, fp32 acc.
// 256 thr = 4 waves in 2x2; each wave 64x64 via 4x4 frags of 16x16x32.
// LDS: As/Bs [128][32] bf16 unpadded (global_load_lds layout contract):
//   wave w, call c stages rows c*64+w*16 .. +15 (lane L -> row +L/4, col (L%4)*8).
// Frag reads (verified layouts): A[m=lane&15][k=quad*8+j]; C/D col=lane&15,
// row=quad*4+reg. 8 ds_read_b128 + 16 MFMA per K-step; 2-barrier loop.
// ---------------------------------------------------------------------------
__device__ __forceinline__ void gemm128(
    const ushort* __restrict__ A, int lda,
    const ushort* __restrict__ Bt, int ldb,
    int m0, int n0, int kmax, f32x4 acc[4][4])
{
    __shared__ __align__(16) ushort As[128 * 32];
    __shared__ __align__(16) ushort Bs[128 * 32];
    const int tid  = threadIdx.x;
    const int lane = tid & 63, wave = tid >> 6;
    const int l16  = lane & 15, quad = lane >> 4;
    const int wr = wave >> 1, wc = wave & 1;
    const int srow = lane >> 2;            // 0..15
    const int scol = (lane & 3) << 3;      // 0,8,16,24 (elements)

#pragma unroll
    for (int i = 0; i < 4; ++i)
#pragma unroll
        for (int j = 0; j < 4; ++j) acc[i][j] = (f32x4){0.f, 0.f, 0.f, 0.f};

    const ushort* Ab = A + (size_t)m0 * lda;
    const ushort* Bb = Bt + (size_t)n0 * ldb;

    for (int k0 = 0; k0 < kmax; k0 += 32) {
#pragma unroll
        for (int c = 0; c < 2; ++c) {
            const int rb = c * 64 + wave * 16;        // wave-uniform row base
            load_lds16(Ab + (size_t)(rb + srow) * lda + k0 + scol, &As[rb * 32]);
            load_lds16(Bb + (size_t)(rb + srow) * ldb + k0 + scol, &Bs[rb * 32]);
        }
        __syncthreads();   // drains vmcnt (global_load_lds) before reads
        bf16x8 a[4], b[4];
#pragma unroll
        for (int i = 0; i < 4; ++i)
            a[i] = *(const bf16x8*)&As[(wr * 64 + i * 16 + l16) * 32 + quad * 8];
#pragma unroll
        for (int j = 0; j < 4; ++j)
            b[j] = *(const bf16x8*)&Bs[(wc * 64 + j * 16 + l16) * 32 + quad * 8];
#pragma unroll
        for (int i = 0; i < 4; ++i)
#pragma unroll
            for (int j = 0; j < 4; ++j)
                acc[i][j] = __builtin_amdgcn_mfma_f32_16x16x32_bf16(
                    a[i], b[j], acc[i][j], 0, 0, 0);
        __syncthreads();   // protect LDS from next-iter staging
    }
}

// ---------------------------------------------------------------------------
// fp32 -> bf16 convert (n multiple of 1024).
// ---------------------------------------------------------------------------
__global__ __launch_bounds__(256) void convert_kernel(
    const float* __restrict__ in, ushort* __restrict__ out, long n)
{
    long i = ((long)blockIdx.x * 256 + threadIdx.x) * 4;
    const long stride = (long)gridDim.x * 1024;
    for (; i < n; i += stride) {
        float4 v = *(const float4*)&in[i];
        out[i + 0] = f2bf(v.x); out[i + 1] = f2bf(v.y);
        out[i + 2] = f2bf(v.z); out[i + 3] = f2bf(v.w);
    }
}

// ---------------------------------------------------------------------------
// Fused convert+transpose of the three per-head weights (z = 0:Wq 1:Wk 2:Wv).
// in fp32 [768,768] (d,e) -> out bf16 [768,768] (e,d) at Wt3 + z*589824.
// grid (24, 24, 3).
// ---------------------------------------------------------------------------
__global__ __launch_bounds__(256) void convt3_kernel(
    const float* __restrict__ Wq, const float* __restrict__ Wk,
    const float* __restrict__ Wv, ushort* __restrict__ Wt3)
{
    const int z = blockIdx.z;
    const float* in = (z == 0) ? Wq : (z == 1) ? Wk : Wv;
    ushort* out = Wt3 + (size_t)z * 589824;
    const int c0 = blockIdx.x * 32;
    const int r0 = blockIdx.y * 32;
    __shared__ ushort t[32][33];
    const int tid = threadIdx.x;
    const int r = tid >> 3;
    const int c = (tid & 7) << 2;
    float4 v = *(const float4*)&in[(size_t)(r0 + r) * D_ + c0 + c];
    t[r][c + 0] = f2bf(v.x); t[r][c + 1] = f2bf(v.y);
    t[r][c + 2] = f2bf(v.z); t[r][c + 3] = f2bf(v.w);
    __syncthreads();
    ushort4 o;
    o.x = t[c + 0][r]; o.y = t[c + 1][r]; o.z = t[c + 2][r]; o.w = t[c + 3][r];
    *(ushort4*)&out[(size_t)(c0 + r) * D_ + r0 + c] = o;
}

// ---------------------------------------------------------------------------
// bf16 transpose of V slabs: in [2048,768] -> out [768,2048], z = slab (2).
// grid (24, 64, 2).
// ---------------------------------------------------------------------------
__global__ __launch_bounds__(256) void transpose_kernel(
    const ushort* __restrict__ in, ushort* __restrict__ out)
{
    const size_t slab = (size_t)blockIdx.z * 1572864;
    const int c0 = blockIdx.x * 32;
    const int r0 = blockIdx.y * 32;
    __shared__ ushort t[32][33];
    const int tid = threadIdx.x;
    const int r = tid >> 3;
    const int c = (tid & 7) << 2;
    ushort4 v = *(const ushort4*)&in[slab + (size_t)(r0 + r) * D_ + c0 + c];
    t[r][c + 0] = v.x; t[r][c + 1] = v.y; t[r][c + 2] = v.z; t[r][c + 3] = v.w;
    __syncthreads();
    ushort4 o;
    o.x = t[c + 0][r]; o.y = t[c + 1][r]; o.z = t[c + 2][r]; o.w = t[c + 3][r];
    *(ushort4*)&out[slab + (size_t)(c0 + r) * S_ + r0 + c] = o;
}

// ---------------------------------------------------------------------------
// QKV projection, one head, both batches, z = 0:Q 1:K 2:V.
// Out[z][s][e] = sum_d Xb[s,d] * Wt3[z][e][d].  grid (6, 32, 3).
// ---------------------------------------------------------------------------
__global__ __launch_bounds__(256, 2) void proj_kernel(
    const ushort* __restrict__ Xb, const ushort* __restrict__ Wt3,
    ushort* __restrict__ QKV3)
{
    const int z = blockIdx.z;
    const int m0 = blockIdx.y * 128, n0 = blockIdx.x * 128;
    f32x4 acc[4][4];
    gemm128(Xb, D_, Wt3 + (size_t)z * 589824, D_, m0, n0, D_, acc);
    const int lane = threadIdx.x & 63, wave = threadIdx.x >> 6;
    const int l16 = lane & 15, quad = lane >> 4;
    const int wr = wave >> 1, wc = wave & 1;
    ushort* out = QKV3 + (size_t)z * 3145728;
#pragma unroll
    for (int i = 0; i < 4; ++i)
#pragma unroll
        for (int j = 0; j < 4; ++j)
#pragma unroll
            for (int r = 0; r < 4; ++r) {
                int rr = m0 + wr * 64 + i * 16 + quad * 4 + r;
                int nc = n0 + wc * 64 + j * 16 + l16;
                out[(size_t)rr * D_ + nc] = f2bf(acc[i][j][r]);
            }
}

// ---------------------------------------------------------------------------
// scores: Sc[slab][q][k] = Q.K^T (bf16, unscaled). grid (16, 16, 2);
// tiles fully above causal diagonal skipped.
// ---------------------------------------------------------------------------
__global__ __launch_bounds__(256, 2) void scores_kernel(
    const ushort* __restrict__ QKV3, ushort* __restrict__ Sc)
{
    const int m0 = blockIdx.y * 128, n0 = blockIdx.x * 128;
    if (n0 >= m0 + 128) return;
    const int slab = blockIdx.z;
    const ushort* Q = QKV3 + (size_t)slab * 1572864;
    const ushort* K = QKV3 + 3145728 + (size_t)slab * 1572864;
    f32x4 acc[4][4];
    gemm128(Q, D_, K, D_, m0, n0, D_, acc);
    ushort* out = Sc + (size_t)slab * 4194304;
    const int lane = threadIdx.x & 63, wave = threadIdx.x >> 6;
    const int l16 = lane & 15, quad = lane >> 4;
    const int wr = wave >> 1, wc = wave & 1;
#pragma unroll
    for (int i = 0; i < 4; ++i)
#pragma unroll
        for (int j = 0; j < 4; ++j)
#pragma unroll
            for (int r = 0; r < 4; ++r) {
                int rr = m0 + wr * 64 + i * 16 + quad * 4 + r;
                int nc = n0 + wc * 64 + j * 16 + l16;
                out[(size_t)rr * S_ + nc] = f2bf(acc[i][j][r]);
            }
}

// ---------------------------------------------------------------------------
// Causal softmax in place (scale 1/sqrt(768)); zeros k>q. grid (2*2048).
// ---------------------------------------------------------------------------
__global__ __launch_bounds__(256) void softmax_kernel(ushort* __restrict__ Sc)
{
    const int slab = blockIdx.x >> 11;
    const int qi   = blockIdx.x & 2047;
    __bf16* row = (__bf16*)(Sc + (size_t)slab * 4194304 + (size_t)qi * S_);
    const float scale = 0.03608439182435161f;  // 1/sqrt(768)
    const int tid = threadIdx.x;
    const int wave = tid >> 6, lane = tid & 63;

    float xv[8];
    float m = -1e30f;
#pragma unroll
    for (int i = 0; i < 8; ++i) {
        int idx = tid + i * 256;
        xv[i] = (idx <= qi) ? (float)row[idx] * scale : -1e30f;
        m = fmaxf(m, xv[i]);
    }
    for (int o = 32; o > 0; o >>= 1) m = fmaxf(m, __shfl_xor(m, o));
    __shared__ float redm[4];
    if (lane == 0) redm[wave] = m;
    __syncthreads();
    m = fmaxf(fmaxf(redm[0], redm[1]), fmaxf(redm[2], redm[3]));

    float e[8];
    float s = 0.f;
#pragma unroll
    for (int i = 0; i < 8; ++i) {
        int idx = tid + i * 256;
        e[i] = (idx <= qi) ? __expf(xv[i] - m) : 0.f;
        s += e[i];
    }
    for (int o = 32; o > 0; o >>= 1) s += __shfl_xor(s, o);
    __shared__ float reds[4];
    if (lane == 0) reds[wave] = s;
    __syncthreads();
    s = reds[0] + reds[1] + reds[2] + reds[3];
    const float inv = 1.f / s;
#pragma unroll
    for (int i = 0; i < 8; ++i) {
        int idx = tid + i * 256;
        row[idx] = (__bf16)(e[i] * inv);
    }
}

// ---------------------------------------------------------------------------
// ctx: Ctx[slab][q][e] = sum_k P[q,k] * Vt[e,k]; k stops at diagonal.
// grid (6, 16, 2).
// ---------------------------------------------------------------------------
__global__ __launch_bounds__(256, 2) void ctx_kernel(
    const ushort* __restrict__ Sc, const ushort* __restrict__ Vt,
    ushort* __restrict__ Ctx)
{
    const int slab = blockIdx.z;
    const int m0 = blockIdx.y * 128, n0 = blockIdx.x * 128;
    f32x4 acc[4][4];
    gemm128(Sc + (size_t)slab * 4194304, S_,
            Vt + (size_t)slab * 1572864, S_, m0, n0, m0 + 128, acc);
    ushort* out = Ctx + (size_t)slab * 1572864;
    const int lane = threadIdx.x & 63, wave = threadIdx.x >> 6;
    const int l16 = lane & 15, quad = lane >> 4;
    const int wr = wave >> 1, wc = wave & 1;
#pragma unroll
    for (int i = 0; i < 4; ++i)
#pragma unroll
        for (int j = 0; j < 4; ++j)
#pragma unroll
            for (int r = 0; r < 4; ++r) {
                int rr = m0 + wr * 64 + i * 16 + quad * 4 + r;
                int nc = n0 + wc * 64 + j * 16 + l16;
                out[(size_t)rr * D_ + nc] = f2bf(acc[i][j][r]);
            }
}

// ---------------------------------------------------------------------------
// Accumulating out-projection: Attn[slab][m][n] += Ctx[m,:] . WoH[n][:]
// (WoH = Wob + h*768, ldb 9216). grid (6, 16, 2).
// ---------------------------------------------------------------------------
__global__ __launch_bounds__(256, 2) void outproj_kernel(
    const ushort* __restrict__ Ctx, const ushort* __restrict__ WoH,
    float* __restrict__ Attn)
{
    const int slab = blockIdx.z;
    const int m0 = blockIdx.y * 128, n0 = blockIdx.x * 128;
    f32x4 acc[4][4];
    gemm128(Ctx + (size_t)slab * 1572864, D_, WoH, HD_, m0, n0, D_, acc);
    float* out = Attn + (size_t)slab * 1572864;
    const int lane = threadIdx.x & 63, wave = threadIdx.x >> 6;
    const int l16 = lane & 15, quad = lane >> 4;
    const int wr = wave >> 1, wc = wave & 1;
#pragma unroll
    for (int i = 0; i < 4; ++i)
#pragma unroll
        for (int j = 0; j < 4; ++j)
#pragma unroll
            for (int r = 0; r < 4; ++r) {
                int rr = m0 + wr * 64 + i * 16 + quad * 4 + r;
                int nc = n0 + wc * 64 + j * 16 + l16;
                out[(size_t)rr * D_ + nc] += acc[i][j][r];
            }
}

// ---------------------------------------------------------------------------
// LayerNorm (no affine, eps=1e-5): fp32 in -> bf16 out. grid (4096).
// ---------------------------------------------------------------------------
__global__ __launch_bounds__(256) void ln_kernel(
    const float* __restrict__ Attn, ushort* __restrict__ Ln)
{
    const int row = blockIdx.x;
    const float* a = Attn + (size_t)row * D_;
    const int tid = threadIdx.x;
    const int wave = tid >> 6, lane = tid & 63;
    float v0 = a[tid], v1 = a[tid + 256], v2 = a[tid + 512];
    float s  = v0 + v1 + v2;
    float sq = v0 * v0 + v1 * v1 + v2 * v2;
    for (int o = 32; o > 0; o >>= 1) { s += __shfl_xor(s, o); sq += __shfl_xor(sq, o); }
    __shared__ float rs[4], rq[4];
    if (lane == 0) { rs[wave] = s; rq[wave] = sq; }
    __syncthreads();
    s  = rs[0] + rs[1] + rs[2] + rs[3];
    sq = rq[0] + rq[1] + rq[2] + rq[3];
    const float mean = s * (1.f / 768.f);
    float var = sq * (1.f / 768.f) - mean * mean;
    var = fmaxf(var, 0.f);
    const float rstd = rsqrtf(var + 1e-5f);
    ushort* o = Ln + (size_t)row * D_;
    o[tid]       = f2bf((v0 - mean) * rstd);
    o[tid + 256] = f2bf((v1 - mean) * rstd);
    o[tid + 512] = f2bf((v2 - mean) * rstd);
}

// ---------------------------------------------------------------------------
// FFN1 + exact GELU: H1 = gelu(Ln . F1b^T), [4096,3072]. grid (24, 32).
// ---------------------------------------------------------------------------
__global__ __launch_bounds__(256, 2) void ffn1_kernel(
    const ushort* __restrict__ Ln, const ushort* __restrict__ F1b,
    ushort* __restrict__ H1)
{
    const int m0 = blockIdx.y * 128, n0 = blockIdx.x * 128;
    f32x4 acc[4][4];
    gemm128(Ln, D_, F1b, D_, m0, n0, D_, acc);
    const int lane = threadIdx.x & 63, wave = threadIdx.x >> 6;
    const int l16 = lane & 15, quad = lane >> 4;
    const int wr = wave >> 1, wc = wave & 1;
#pragma unroll
    for (int i = 0; i < 4; ++i)
#pragma unroll
        for (int j = 0; j < 4; ++j)
#pragma unroll
            for (int r = 0; r < 4; ++r) {
                int rr = m0 + wr * 64 + i * 16 + quad * 4 + r;
                int nc = n0 + wc * 64 + j * 16 + l16;
                float v = acc[i][j][r];
                float gl = 0.5f * v * (1.f + erff(v * 0.70710678118654752f));
                H1[(size_t)rr * FF_ + nc] = f2bf(gl);
            }
}

// ---------------------------------------------------------------------------
// FFN2 + residual -> d_out fp32. grid (6, 32).
// ---------------------------------------------------------------------------
__global__ __launch_bounds__(256, 2) void ffn2_kernel(
    const ushort* __restrict__ H1, const ushort* __restrict__ F2b,
    const float* __restrict__ Attn, float* __restrict__ Out)
{
    const int m0 = blockIdx.y * 128, n0 = blockIdx.x * 128;
    f32x4 acc[4][4];
    gemm128(H1, FF_, F2b, FF_, m0, n0, FF_, acc);
    const int lane = threadIdx.x & 63, wave = threadIdx.x >> 6;
    const int l16 = lane & 15, quad = lane >> 4;
    const int wr = wave >> 1, wc = wave & 1;
#pragma unroll
    for (int i = 0; i < 4; ++i)
#pragma unroll
        for (int j = 0; j < 4; ++j)
#pragma unroll
            for (int r = 0; r < 4; ++r) {
                size_t idx = (size_t)(m0 + wr * 64 + i * 16 + quad * 4 + r) * D_
                           + n0 + wc * 64 + j * 16 + l16;
                Out[idx] = acc[i][j][r] + Attn[idx];
            }
}

// ---------------------------------------------------------------------------
// kernel_launch — 128-tile MFMA core + z-batched launches (~92 total).
// Workspace: 94,240,768 B (FFN transients overlap attention transients).
// ---------------------------------------------------------------------------
extern "C" void kernel_launch(void* const* d_in, const int* in_sizes, int n_in,
                              void* d_out, int out_size, void* d_ws, size_t ws_size,
                              hipStream_t stream)
{
    // identify inputs by element count (x=3145728, ff=2359296, weights rest)
    int ix = -1, iw[4], nw = 0, iff[2], nf = 0;
    for (int i = 0; i < 7; ++i) {
        long sz = in_sizes[i];
        if (sz == 3145728L) ix = i;
        else if (sz == 2359296L) { if (nf < 2) iff[nf++] = i; }
        else { if (nw < 4) iw[nw++] = i; }
    }
    if (ix < 0 || nw != 4 || nf != 2) {
        ix = 0; iw[0] = 1; iw[1] = 2; iw[2] = 3; iw[3] = 4; iff[0] = 5; iff[1] = 6;
    }
    const float* x; const float *Wq, *Wk, *Wv, *Wo, *F1, *F2;
    x  = (const float*)d_in[ix];
    F1 = (const float*)d_in[iff[0]];
    F2 = (const float*)d_in[iff[1]];
    if (ix == 0) {           // dict order
        Wq = (const float*)d_in[iw[0]]; Wk = (const float*)d_in[iw[1]];
        Wv = (const float*)d_in[iw[2]]; Wo = (const float*)d_in[iw[3]];
    } else {                 // alphabetical
        Wk = (const float*)d_in[iw[0]]; Wo = (const float*)d_in[iw[1]];
        Wq = (const float*)d_in[iw[2]]; Wv = (const float*)d_in[iw[3]];
    }

    char* p = (char*)d_ws;
    ushort* Xb   = (ushort*)p;  p += 6291456;    // [4096,768] bf16
    ushort* Wob  = (ushort*)p;  p += 14155776;   // [768,9216] bf16
    ushort* F1b  = (ushort*)p;  p += 4718592;    // [3072,768] bf16
    ushort* F2b  = (ushort*)p;  p += 4718592;    // [768,3072] bf16
    float*  Attn = (float*)p;   p += 12582912;   // [2][2048,768] fp32
    ushort* Wt3  = (ushort*)p;  p += 3538944;    // [3][768,768] bf16 (W^T)
    char* trans = p;                             // transient region 48,234,496 B
    ushort* QKV3 = (ushort*)trans;               // [3][4096,768]  18,874,368
    ushort* Vt   = (ushort*)(trans + 18874368);  // [2][768,2048]   6,291,456
    ushort* Ctx  = (ushort*)(trans + 25165824);  // [2][2048,768]   6,291,456
    ushort* Sc   = (ushort*)(trans + 31457280);  // [2][2048,2048] 16,777,216
    // FFN phase overlaps the same region:
    ushort* Ln   = (ushort*)trans;               // [4096,768]      6,291,456
    ushort* H1   = (ushort*)(trans + 6291456);   // [4096,3072]    25,165,824

    dim3 blk(256);
    hipMemsetAsync(Attn, 0, 12582912, stream);

    convert_kernel<<<dim3(1024), blk, 0, stream>>>(x,  Xb,  3145728L);
    convert_kernel<<<dim3(1024), blk, 0, stream>>>(Wo, Wob, 7077888L);
    convert_kernel<<<dim3(1024), blk, 0, stream>>>(F1, F1b, 2359296L);
    convert_kernel<<<dim3(1024), blk, 0, stream>>>(F2, F2b, 2359296L);

    for (int h = 0; h < 12; ++h) {
        const size_t wo = (size_t)h * D_ * D_;
        convt3_kernel<<<dim3(24, 24, 3), blk, 0, stream>>>(
            Wq + wo, Wk + wo, Wv + wo, Wt3);
        proj_kernel<<<dim3(6, 32, 3), blk, 0, stream>>>(Xb, Wt3, QKV3);
        transpose_kernel<<<dim3(24, 64, 2), blk, 0, stream>>>(
            QKV3 + 2 * 3145728, Vt);
        scores_kernel<<<dim3(16, 16, 2), blk, 0, stream>>>(QKV3, Sc);
        softmax_kernel<<<dim3(4096), blk, 0, stream>>>(Sc);
        ctx_kernel<<<dim3(6, 16, 2), blk, 0, stream>>>(Sc, Vt, Ctx);
        outproj_kernel<<<dim3(6, 16, 2), blk, 0, stream>>>(
            Ctx, Wob + (size_t)h * D_, Attn);
    }

    ln_kernel<<<dim3(4096), blk, 0, stream>>>(Attn, Ln);
    ffn1_kernel<<<dim3(24, 32), blk, 0, stream>>>(Ln, F1b, H1);
    ffn2_kernel<<<dim3(6, 32), blk, 0, stream>>>(H1, F2b, Attn, (float*)d_out);
}